// Round 4
// baseline (264.198 us; speedup 1.0000x reference)
//
#include <hip/hip_runtime.h>
#include <stdint.h>

#define B_    16
#define AT_   96
#define NBR_  12
#define FN_   64
#define FE_   64
#define M1    (B_*AT_*NBR_)   /* 18432 */
#define R_    (B_*AT_)        /* 1536  */
#define K1Q   128             /* layer-1 input features (bytes per row) */
#define N1    512             /* H1 */
#define K2Q   512
#define N2    128
#define SPLIT2 4

typedef _Float16 f16x8 __attribute__((ext_vector_type(8)));
typedef _Float16 f16x2 __attribute__((ext_vector_type(2)));
typedef float    f32x4 __attribute__((ext_vector_type(4)));

/* ---- workspace layout (bytes) ---- */
#define OFF_SCAL  0u
#define OFF_B1R   256u                                  /* fp32 512  */
#define OFF_B2R   (OFF_B1R + 2048u)                     /* fp32 128  */
#define OFF_Q1    4096u                                 /* u8 M1*128 = 2.25 MB */
#define OFF_W1E   (OFF_Q1  + (size_t)M1*K1Q)            /* fp16 512*1024 = 1 MB */
#define OFF_W2E   (OFF_W1E + (size_t)N1*K1Q*8*2)        /* fp16 128*4096 = 1 MB */
#define OFF_Q2    (OFF_W2E + (size_t)N2*K2Q*8*2)        /* u8 M1*512 = 9 MB */
#define OFF_H     (OFF_Q2  + (size_t)M1*K2Q)            /* fp16 M1*512 = 18.87 MB */
#define OFF_ZP    OFF_H                                  /* fp16 4*M1*128 = 18.87 MB; h dead after quant_h */
#define OFF_NS    (OFF_H   + (size_t)M1*N1*2)           /* fp32 1536*64 */

__device__ __forceinline__ unsigned int enc_f(float f) {
    unsigned int u = __float_as_uint(f);
    return (u & 0x80000000u) ? ~u : (u | 0x80000000u);
}
__device__ __forceinline__ float dec_f(unsigned int u) {
    return __uint_as_float((u & 0x80000000u) ? (u & 0x7FFFFFFFu) : ~u);
}

/* init scal + zero bias accumulators (ws is poisoned 0xAA every launch) */
__global__ void k_init(unsigned int* scal, float* b1raw, float* b2raw) {
    int t = threadIdx.x;
    if (t == 0) { scal[0] = 0xFFFFFFFFu; scal[1] = 0u; scal[2] = 0xFFFFFFFFu; scal[3] = 0u; }
    if (t < N1) b1raw[t] = 0.f;
    if (t < N2) b2raw[t] = 0.f;
}

__global__ __launch_bounds__(256) void k_minmax_c1(const float* __restrict__ node,
                                                   const float* __restrict__ edge,
                                                   unsigned int* __restrict__ scal) {
    const int nn4 = (B_*AT_*FN_)/4;       /* 24576  */
    const int tot4 = nn4 + (M1*FE_)/4;    /* 319488 */
    float mn = 3.0e38f, mx = -3.0e38f;
    for (int idx = blockIdx.x*blockDim.x + threadIdx.x; idx < tot4; idx += gridDim.x*blockDim.x) {
        float4 x = (idx < nn4) ? ((const float4*)node)[idx] : ((const float4*)edge)[idx - nn4];
        mn = fminf(mn, fminf(fminf(x.x, x.y), fminf(x.z, x.w)));
        mx = fmaxf(mx, fmaxf(fmaxf(x.x, x.y), fmaxf(x.z, x.w)));
    }
    __shared__ float smn[256], smx[256];
    smn[threadIdx.x] = mn; smx[threadIdx.x] = mx; __syncthreads();
    for (int s = 128; s > 0; s >>= 1) {
        if (threadIdx.x < s) {
            smn[threadIdx.x] = fminf(smn[threadIdx.x], smn[threadIdx.x+s]);
            smx[threadIdx.x] = fmaxf(smx[threadIdx.x], smx[threadIdx.x+s]);
        }
        __syncthreads();
    }
    if (threadIdx.x == 0) { atomicMin(&scal[0], enc_f(smn[0])); atomicMax(&scal[1], enc_f(smx[0])); }
}

/* expanded fp16 weights, o-major: We[o][k=i*8+b] = fp16( (w+0.1|w|eps_b) * 2^b * s )
   + fused bias-sum accumulation (wave-reduce, 1 atomic per wave) */
template<int KQ, int N, int SBASE, bool USE_SECOND>
__global__ __launch_bounds__(256) void k_prep_w16(const float* __restrict__ w_clean,
                                                  const float* __restrict__ eps,
                                                  const unsigned int* __restrict__ scal,
                                                  float* __restrict__ braw,
                                                  _Float16* __restrict__ We) {
    int idx = blockIdx.x*blockDim.x + threadIdx.x;   /* one thread per (o,i) */
    if (idx >= N*KQ) return;
    int o = idx / KQ;
    int i = idx % KQ;
    float mn = dec_f(scal[SBASE]), mx = dec_f(scal[SBASE+1]);
    float s = (mx - mn) * (1.0f/255.0f);
    float w = w_clean[idx];
    float aw = fabsf(w) * 0.1f;
    union { _Float16 h[8]; uint4 u; } pk;
    float p = s;
    float v7 = 0.f;
    #pragma unroll
    for (int b = 0; b < 8; b++) {
        float e = eps[(size_t)b*N*KQ + idx];
        float v = w + e*aw;
        if (b == 7) v7 = v;
        pk.h[b] = (_Float16)(v * p);
        p *= 2.0f;
    }
    *(uint4*)&We[((size_t)o*KQ + i)*8] = pk.u;
    float bv = USE_SECOND ? w_clean[(size_t)N*KQ + idx] : v7;
    #pragma unroll
    for (int off = 32; off > 0; off >>= 1) bv += __shfl_down(bv, off);
    if ((threadIdx.x & 63) == 0) atomicAdd(&braw[o], bv);
}

/* quantize c1 -> q1 m-major [m][128] bytes; thread per output dword */
__global__ __launch_bounds__(256) void k_quant_c1(const float* __restrict__ node,
                                                  const float* __restrict__ edge,
                                                  const unsigned int* __restrict__ scal,
                                                  unsigned int* __restrict__ q1) {
    int idx = blockIdx.x*256 + threadIdx.x;   /* < M1*32 */
    int m = idx >> 5, dw = idx & 31;
    const float mn = dec_f(scal[0]), rng = dec_f(scal[1]) - mn;
    float4 x;
    if (dw < 16) x = *(const float4*)&node[(m/NBR_)*FN_ + dw*4];
    else         x = *(const float4*)&edge[(size_t)m*FE_ + (dw-16)*4];
    unsigned int b0 = (unsigned char)(int)((x.x - mn) / rng * 255.0f);
    unsigned int b1 = (unsigned char)(int)((x.y - mn) / rng * 255.0f);
    unsigned int b2 = (unsigned char)(int)((x.z - mn) / rng * 255.0f);
    unsigned int b3 = (unsigned char)(int)((x.w - mn) / rng * 255.0f);
    q1[idx] = b0 | (b1 << 8) | (b2 << 16) | (b3 << 24);
}

/* quantize fp16 h -> q2 m-major [m][512] bytes; thread per 8 elements */
__global__ __launch_bounds__(256) void k_quant_h(const _Float16* __restrict__ h,
                                                 const unsigned int* __restrict__ scal,
                                                 unsigned int* __restrict__ q2) {
    int idx = blockIdx.x*256 + threadIdx.x;   /* < M1*512/8 */
    const float mn = dec_f(scal[2]), rng = dec_f(scal[3]) - mn;
    f16x8 v = *(const f16x8*)(h + (size_t)idx*8);
    unsigned int lo = 0, hi = 0;
    #pragma unroll
    for (int j = 0; j < 4; j++) {
        float x = (float)v[j];
        lo |= ((unsigned int)(unsigned char)(int)((x - mn) / rng * 255.0f)) << (j*8);
    }
    #pragma unroll
    for (int j = 0; j < 4; j++) {
        float x = (float)v[4+j];
        hi |= ((unsigned int)(unsigned char)(int)((x - mn) / rng * 255.0f)) << (j*8);
    }
    uint2 o; o.x = lo; o.y = hi;
    *(uint2*)&q2[idx*2] = o;
}

__device__ __forceinline__ f16x8 expand_byte(unsigned int byte) {
    /* 8 bits -> 8 packed fp16 in {0.0, 1.0}; pairs via r2 = b | b<<15 */
    unsigned int r2 = byte | (byte << 15);
    union { unsigned int u[4]; f16x8 h; } t;
    t.u[0] = ( r2       & 0x00010001u) * 0x3C00u;
    t.u[1] = ((r2 >> 2) & 0x00010001u) * 0x3C00u;
    t.u[2] = ((r2 >> 4) & 0x00010001u) * 0x3C00u;
    t.u[3] = ((r2 >> 6) & 0x00010001u) * 0x3C00u;
    return t.h;
}

/* Barrier-free direct-load MFMA bit-plane GEMM.
   No LDS, no __syncthreads in the K-loop: B frags load straight from L2-resident
   W (o-major => frag = 16B contiguous per lane), A q-bytes straight from q.
   Block = 4 waves stacked in m (share B stream via L1); wave tile 64m x 64n.
   __launch_bounds__(256,3): ~<=170 VGPR, no spill; 576 blocks all resident. */
template<int KQ, int N, int SPLITK, bool EPI1>
__global__ __launch_bounds__(256, 3) void kgd(const unsigned char* __restrict__ q,
                                              const _Float16* __restrict__ W,
                                              const float* __restrict__ braw,
                                              void* __restrict__ outv,
                                              unsigned int* __restrict__ scal) {
    constexpr int KP  = KQ * 8;        /* total bit-planes */
    constexpr int KPS = KP / SPLITK;   /* planes per z-split (1024 both layers) */
    const int tid  = threadIdx.x;
    const int lane = tid & 63;
    const int w    = tid >> 6;
    const int l15  = lane & 15;
    const int lq   = lane >> 4;
    const int sh8  = lq * 8;
    const int m0   = blockIdx.x * 256 + w * 64;
    const int o0   = blockIdx.y * 64;
    const int kbase = blockIdx.z * KPS;

    f32x4 acc[4][4] = {};

    /* per-lane 32-bit offsets; s-base + v-offset addressing */
    unsigned int aoff[4];
    #pragma unroll
    for (int mf = 0; mf < 4; ++mf)
        aoff[mf] = (unsigned int)(m0 + mf*16 + l15) * KQ + (kbase >> 3);
    unsigned int boff[8];
    #pragma unroll
    for (int nf = 0; nf < 4; ++nf)
        #pragma unroll
        for (int kf = 0; kf < 2; ++kf)
            boff[nf*2+kf] = (unsigned int)(o0 + nf*16 + l15) * KP + kbase + kf*32 + lq*8;

    #pragma unroll 1
    for (int it = 0; it < KPS/64; ++it) {
        uint2 qd[4];
        #pragma unroll
        for (int mf = 0; mf < 4; ++mf)
            qd[mf] = *(const uint2*)(q + aoff[mf] + it*8);
        f16x8 bf[8];
        #pragma unroll
        for (int j = 0; j < 8; ++j)
            bf[j] = *(const f16x8*)(W + boff[j] + it*64);
        #pragma unroll
        for (int kf = 0; kf < 2; ++kf) {
            #pragma unroll
            for (int mf = 0; mf < 4; ++mf) {
                unsigned int byte = ((kf ? qd[mf].y : qd[mf].x) >> sh8) & 0xFFu;
                f16x8 a = expand_byte(byte);
                #pragma unroll
                for (int nf = 0; nf < 4; ++nf)
                    acc[mf][nf] = __builtin_amdgcn_mfma_f32_16x16x32_f16(a, bf[nf*2+kf], acc[mf][nf], 0, 0, 0);
            }
        }
    }

    /* epilogue: C/D layout col = lane&15, row = (lane>>4)*4 + r  (m89) */
    if (EPI1) {
        __shared__ float red[512];
        _Float16* out = (_Float16*)outv;
        const float mn1 = dec_f(scal[0]);
        float bv[4];
        #pragma unroll
        for (int nf = 0; nf < 4; ++nf) bv[nf] = mn1 * braw[o0 + nf*16 + l15];
        float tmn = 3.0e38f, tmx = -3.0e38f;
        #pragma unroll
        for (int mf = 0; mf < 4; ++mf) {
            const int mr = m0 + mf*16 + lq*4;
            #pragma unroll
            for (int nf = 0; nf < 4; ++nf) {
                const int oc = o0 + nf*16 + l15;
                #pragma unroll
                for (int r = 0; r < 4; ++r) {
                    float v = fmaxf(acc[mf][nf][r] + bv[nf], 0.0f);
                    _Float16 v16 = (_Float16)v;
                    float vr = (float)v16;          /* min/max of fp16-rounded h */
                    tmn = fminf(tmn, vr); tmx = fmaxf(tmx, vr);
                    out[(size_t)(mr + r)*N + oc] = v16;
                }
            }
        }
        red[tid] = tmn; red[256 + tid] = tmx;
        __syncthreads();
        for (int s = 128; s > 0; s >>= 1) {
            if (tid < s) {
                red[tid]       = fminf(red[tid],       red[tid + s]);
                red[256 + tid] = fmaxf(red[256 + tid], red[256 + tid + s]);
            }
            __syncthreads();
        }
        if (tid == 0) { atomicMin(&scal[2], enc_f(red[0])); atomicMax(&scal[3], enc_f(red[256])); }
    } else {
        _Float16* op = (_Float16*)outv + (size_t)blockIdx.z * ((size_t)M1 * N);
        #pragma unroll
        for (int mf = 0; mf < 4; ++mf) {
            const int mr = m0 + mf*16 + lq*4;
            #pragma unroll
            for (int nf = 0; nf < 4; ++nf) {
                const int oc = o0 + nf*16 + l15;
                #pragma unroll
                for (int r = 0; r < 4; ++r)
                    op[(size_t)(mr + r)*N + oc] = (_Float16)acc[mf][nf][r];
            }
        }
    }
}

/* gate/extract from fp16 split-K partials -> sigmoid*tanh*mask, sum over neighbors.
   2 features per thread, packed fp16x2 loads. */
__global__ __launch_bounds__(256) void k_nbr(const _Float16* __restrict__ zp,
                                             const float* __restrict__ b2raw,
                                             const unsigned int* __restrict__ scal,
                                             const float* __restrict__ mask,
                                             float* __restrict__ ns) {
    const size_t SP = (size_t)M1 * N2;
    int tid = threadIdx.x;
    int r = blockIdx.x*8 + (tid >> 5);    /* 0..1535 */
    int f2 = (tid & 31) * 2;
    const float mn2 = dec_f(scal[2]);
    float bg0 = mn2 * b2raw[f2],      bg1 = mn2 * b2raw[f2+1];
    float be0 = mn2 * b2raw[64 + f2], be1 = mn2 * b2raw[65 + f2];
    float s0 = 0.f, s1 = 0.f;
    #pragma unroll
    for (int n = 0; n < NBR_; n++) {
        int m = r*NBR_ + n;
        size_t base = (size_t)m * N2;
        float g0 = bg0, g1 = bg1, e0 = be0, e1 = be1;
        #pragma unroll
        for (int z = 0; z < SPLIT2; z++) {
            f16x2 gv = *(const f16x2*)(zp + z*SP + base + f2);
            f16x2 ev = *(const f16x2*)(zp + z*SP + base + 64 + f2);
            g0 += (float)gv[0]; g1 += (float)gv[1];
            e0 += (float)ev[0]; e1 += (float)ev[1];
        }
        float mk = mask[m];
        s0 += (1.0f / (1.0f + expf(-g0))) * tanhf(e0) * mk;
        s1 += (1.0f / (1.0f + expf(-g1))) * tanhf(e1) * mk;
    }
    float2 o; o.x = s0; o.y = s1;
    *(float2*)&ns[r*64 + f2] = o;
}

/* BatchNorm (batch stats over 1536 rows) + residual + relu; one block per feature */
__global__ __launch_bounds__(256) void k_bn(const float* __restrict__ ns,
                                            const float* __restrict__ node,
                                            const float* __restrict__ gamma,
                                            const float* __restrict__ beta,
                                            float* __restrict__ out) {
    int f = blockIdx.x;
    int tid = threadIdx.x;
    float x[6];
    float s = 0.f, ss = 0.f;
    #pragma unroll
    for (int k = 0; k < 6; k++) {
        int r = tid + k*256;
        x[k] = ns[r*64 + f];
        s += x[k]; ss += x[k]*x[k];
    }
    __shared__ float rs[256], rss[256];
    rs[tid] = s; rss[tid] = ss; __syncthreads();
    for (int st = 128; st > 0; st >>= 1) {
        if (tid < st) { rs[tid] += rs[tid+st]; rss[tid] += rss[tid+st]; }
        __syncthreads();
    }
    float mean = rs[0] / 1536.0f;
    float var  = rss[0] / 1536.0f - mean*mean;
    float denom = sqrtf(var + 1e-5f);
    float g = gamma[f], bt = beta[f];
    #pragma unroll
    for (int k = 0; k < 6; k++) {
        int r = tid + k*256;
        float v = node[r*64 + f] + ((x[k] - mean) / denom * g + bt);
        out[r*64 + f] = fmaxf(v, 0.f);
    }
}

extern "C" void kernel_launch(void* const* d_in, const int* in_sizes, int n_in,
                              void* d_out, int out_size, void* d_ws, size_t ws_size,
                              hipStream_t stream) {
    const float* node  = (const float*)d_in[0];
    const float* edge  = (const float*)d_in[1];
    const float* mask  = (const float*)d_in[2];
    const float* cond1 = (const float*)d_in[3];
    const float* cond2 = (const float*)d_in[4];
    const float* eps1  = (const float*)d_in[5];
    const float* eps2  = (const float*)d_in[6];
    const float* gamma = (const float*)d_in[7];
    const float* beta  = (const float*)d_in[8];
    float* out = (float*)d_out;
    char* ws = (char*)d_ws;

    unsigned int*  scal = (unsigned int*)(ws + OFF_SCAL);
    float* b1raw = (float*)(ws + OFF_B1R);
    float* b2raw = (float*)(ws + OFF_B2R);
    unsigned char* q1 = (unsigned char*)(ws + OFF_Q1);
    _Float16* W1e = (_Float16*)(ws + OFF_W1E);
    _Float16* W2e = (_Float16*)(ws + OFF_W2E);
    unsigned char* q2 = (unsigned char*)(ws + OFF_Q2);
    _Float16* h  = (_Float16*)(ws + OFF_H);
    _Float16* zp = (_Float16*)(ws + OFF_ZP);
    float*    ns = (float*)(ws + OFF_NS);

    k_init<<<1, 1024, 0, stream>>>(scal, b1raw, b2raw);
    k_minmax_c1<<<512, 256, 0, stream>>>(node, edge, scal);
    k_prep_w16<K1Q, N1, 0, false><<<(N1*K1Q + 255)/256, 256, 0, stream>>>(cond1, eps1, scal, b1raw, W1e);
    k_quant_c1<<<(M1*32)/256, 256, 0, stream>>>(node, edge, scal, (unsigned int*)q1);
    kgd<K1Q, N1, 1, true><<<dim3(M1/256, N1/64, 1), 256, 0, stream>>>(q1, W1e, b1raw, h, scal);
    k_prep_w16<K2Q, N2, 2, true><<<(N2*K2Q + 255)/256, 256, 0, stream>>>(cond2, eps2, scal, b2raw, W2e);
    k_quant_h<<<(M1*512/8)/256, 256, 0, stream>>>(h, scal, (unsigned int*)q2);
    kgd<K2Q, N2, SPLIT2, false><<<dim3(M1/256, N2/64, SPLIT2), 256, 0, stream>>>(q2, W2e, b2raw, zp, scal);
    k_nbr<<<R_/8, 256, 0, stream>>>(zp, b2raw, scal, mask, ns);
    k_bn<<<64, 256, 0, stream>>>(ns, node, gamma, beta, out);
}

// Round 5
// 231.582 us; speedup vs baseline: 1.1408x; 1.1408x over previous
//
#include <hip/hip_runtime.h>
#include <stdint.h>

#define B_    16
#define AT_   96
#define NBR_  12
#define FN_   64
#define FE_   64
#define M1    (B_*AT_*NBR_)   /* 18432 */
#define R_    (B_*AT_)        /* 1536  */
#define K1Q   128             /* layer-1 input features (bytes per row) */
#define N1    512             /* H1 */
#define K2Q   512
#define N2    128
#define SPLIT2 4

typedef _Float16 f16x8 __attribute__((ext_vector_type(8)));
typedef _Float16 f16x2 __attribute__((ext_vector_type(2)));
typedef float    f32x4 __attribute__((ext_vector_type(4)));

/* ---- workspace layout (bytes) ---- */
#define OFF_SCAL  0u
#define OFF_B1R   256u                                  /* fp32 512  */
#define OFF_B2R   (OFF_B1R + 2048u)                     /* fp32 128  */
#define OFF_Q1    4096u                                 /* u8 M1*128 = 2.25 MB */
#define OFF_W1E   (OFF_Q1  + (size_t)M1*K1Q)            /* fp16 512*1024 = 1 MB */
#define OFF_W2E   (OFF_W1E + (size_t)N1*K1Q*8*2)        /* fp16 128*4096 = 1 MB */
#define OFF_Q2    (OFF_W2E + (size_t)N2*K2Q*8*2)        /* u8 M1*512 = 9 MB */
#define OFF_H     (OFF_Q2  + (size_t)M1*K2Q)            /* fp16 M1*512 = 18.87 MB */
#define OFF_ZP    OFF_H                                  /* fp16 4*M1*128 = 18.87 MB; h dead after quant_h */
#define OFF_NS    (OFF_H   + (size_t)M1*N1*2)           /* fp32 1536*64 */

__device__ __forceinline__ unsigned int enc_f(float f) {
    unsigned int u = __float_as_uint(f);
    return (u & 0x80000000u) ? ~u : (u | 0x80000000u);
}
__device__ __forceinline__ float dec_f(unsigned int u) {
    return __uint_as_float((u & 0x80000000u) ? (u & 0x7FFFFFFFu) : ~u);
}

/* init scal + zero bias accumulators (ws is poisoned 0xAA every launch) */
__global__ void k_init(unsigned int* scal, float* b1raw, float* b2raw) {
    int t = threadIdx.x;
    if (t == 0) { scal[0] = 0xFFFFFFFFu; scal[1] = 0u; scal[2] = 0xFFFFFFFFu; scal[3] = 0u; }
    if (t < N1) b1raw[t] = 0.f;
    if (t < N2) b2raw[t] = 0.f;
}

__global__ __launch_bounds__(256) void k_minmax_c1(const float* __restrict__ node,
                                                   const float* __restrict__ edge,
                                                   unsigned int* __restrict__ scal) {
    const int nn4 = (B_*AT_*FN_)/4;       /* 24576  */
    const int tot4 = nn4 + (M1*FE_)/4;    /* 319488 */
    float mn = 3.0e38f, mx = -3.0e38f;
    for (int idx = blockIdx.x*blockDim.x + threadIdx.x; idx < tot4; idx += gridDim.x*blockDim.x) {
        float4 x = (idx < nn4) ? ((const float4*)node)[idx] : ((const float4*)edge)[idx - nn4];
        mn = fminf(mn, fminf(fminf(x.x, x.y), fminf(x.z, x.w)));
        mx = fmaxf(mx, fmaxf(fmaxf(x.x, x.y), fmaxf(x.z, x.w)));
    }
    __shared__ float smn[256], smx[256];
    smn[threadIdx.x] = mn; smx[threadIdx.x] = mx; __syncthreads();
    for (int s = 128; s > 0; s >>= 1) {
        if (threadIdx.x < s) {
            smn[threadIdx.x] = fminf(smn[threadIdx.x], smn[threadIdx.x+s]);
            smx[threadIdx.x] = fmaxf(smx[threadIdx.x], smx[threadIdx.x+s]);
        }
        __syncthreads();
    }
    if (threadIdx.x == 0) { atomicMin(&scal[0], enc_f(smn[0])); atomicMax(&scal[1], enc_f(smx[0])); }
}

/* expanded fp16 weights, o-major: We[o][k=i*8+b] = fp16( (w+0.1|w|eps_b) * 2^b * s )
   + fused bias-sum accumulation (wave-reduce, 1 atomic per wave) */
template<int KQ, int N, int SBASE, bool USE_SECOND>
__global__ __launch_bounds__(256) void k_prep_w16(const float* __restrict__ w_clean,
                                                  const float* __restrict__ eps,
                                                  const unsigned int* __restrict__ scal,
                                                  float* __restrict__ braw,
                                                  _Float16* __restrict__ We) {
    int idx = blockIdx.x*blockDim.x + threadIdx.x;   /* one thread per (o,i) */
    if (idx >= N*KQ) return;
    int o = idx / KQ;
    float mn = dec_f(scal[SBASE]), mx = dec_f(scal[SBASE+1]);
    float s = (mx - mn) * (1.0f/255.0f);
    float w = w_clean[idx];
    float aw = fabsf(w) * 0.1f;
    union { _Float16 h[8]; uint4 u; } pk;
    float p = s;
    float v7 = 0.f;
    #pragma unroll
    for (int b = 0; b < 8; b++) {
        float e = eps[(size_t)b*N*KQ + idx];
        float v = w + e*aw;
        if (b == 7) v7 = v;
        pk.h[b] = (_Float16)(v * p);
        p *= 2.0f;
    }
    *(uint4*)&We[(size_t)idx*8] = pk.u;
    float bv = USE_SECOND ? w_clean[(size_t)N*KQ + idx] : v7;
    #pragma unroll
    for (int off = 32; off > 0; off >>= 1) bv += __shfl_down(bv, off);
    if ((threadIdx.x & 63) == 0) atomicAdd(&braw[o], bv);
}

/* quantize c1 -> q1 m-major [m][128] bytes; thread per output dword */
__global__ __launch_bounds__(256) void k_quant_c1(const float* __restrict__ node,
                                                  const float* __restrict__ edge,
                                                  const unsigned int* __restrict__ scal,
                                                  unsigned int* __restrict__ q1) {
    int idx = blockIdx.x*256 + threadIdx.x;   /* < M1*32 */
    int m = idx >> 5, dw = idx & 31;
    const float mn = dec_f(scal[0]), rng = dec_f(scal[1]) - mn;
    float4 x;
    if (dw < 16) x = *(const float4*)&node[(m/NBR_)*FN_ + dw*4];
    else         x = *(const float4*)&edge[(size_t)m*FE_ + (dw-16)*4];
    unsigned int b0 = (unsigned char)(int)((x.x - mn) / rng * 255.0f);
    unsigned int b1 = (unsigned char)(int)((x.y - mn) / rng * 255.0f);
    unsigned int b2 = (unsigned char)(int)((x.z - mn) / rng * 255.0f);
    unsigned int b3 = (unsigned char)(int)((x.w - mn) / rng * 255.0f);
    q1[idx] = b0 | (b1 << 8) | (b2 << 16) | (b3 << 24);
}

/* quantize fp16 h -> q2 m-major [m][512] bytes; thread per 8 elements */
__global__ __launch_bounds__(256) void k_quant_h(const _Float16* __restrict__ h,
                                                 const unsigned int* __restrict__ scal,
                                                 unsigned int* __restrict__ q2) {
    int idx = blockIdx.x*256 + threadIdx.x;   /* < M1*512/8 */
    const float mn = dec_f(scal[2]), rng = dec_f(scal[3]) - mn;
    f16x8 v = *(const f16x8*)(h + (size_t)idx*8);
    unsigned int lo = 0, hi = 0;
    #pragma unroll
    for (int j = 0; j < 4; j++) {
        float x = (float)v[j];
        lo |= ((unsigned int)(unsigned char)(int)((x - mn) / rng * 255.0f)) << (j*8);
    }
    #pragma unroll
    for (int j = 0; j < 4; j++) {
        float x = (float)v[4+j];
        hi |= ((unsigned int)(unsigned char)(int)((x - mn) / rng * 255.0f)) << (j*8);
    }
    uint2 o; o.x = lo; o.y = hi;
    *(uint2*)&q2[idx*2] = o;
}

__device__ __forceinline__ f16x8 expand_byte(unsigned int byte) {
    /* 8 bits -> 8 packed fp16 in {0.0, 1.0}; pairs via r2 = b | b<<15 */
    unsigned int r2 = byte | (byte << 15);
    union { unsigned int u[4]; f16x8 h; } t;
    t.u[0] = ( r2       & 0x00010001u) * 0x3C00u;
    t.u[1] = ((r2 >> 2) & 0x00010001u) * 0x3C00u;
    t.u[2] = ((r2 >> 4) & 0x00010001u) * 0x3C00u;
    t.u[3] = ((r2 >> 6) & 0x00010001u) * 0x3C00u;
    return t.h;
}

/* MFMA bit-plane GEMM, v5: wave-private LDS A staging + pipelined direct-B.
   Block = 4 waves stacked in m (64 rows each), n-tile 64, K/z = 1024 planes.
   Prologue: each wave stages its 64x128B q-slice into private LDS (coalesced
   dwordx4 reads; NO __syncthreads ever -- same-wave lgkmcnt only). Row stride
   136 -> in-loop ds_read_b64 is conflict-free (16 even banks, 4-way bcast).
   K-loop: B frags direct from L2-resident o-major W (16B contiguous/lane),
   register double-buffered one iter ahead; 32 MFMA per iter. */
template<int KQ, int N, int SPLITK, bool EPI1>
__global__ __launch_bounds__(256, 3) void kge(const unsigned char* __restrict__ q,
                                              const _Float16* __restrict__ W,
                                              const float* __restrict__ braw,
                                              void* __restrict__ outv,
                                              unsigned int* __restrict__ scal) {
    constexpr int KP  = KQ * 8;        /* total bit-planes */
    constexpr int KPS = KP / SPLITK;   /* planes per z-split (1024 both layers) */
    constexpr int NIT = KPS / 64;      /* 16 */
    __shared__ __align__(16) unsigned char ldsA[4*64*136];   /* 34816 B */

    const int tid  = threadIdx.x;
    const int lane = tid & 63;
    const int w    = tid >> 6;
    const int l15  = lane & 15;
    const int lq   = lane >> 4;
    const int sh8  = lq * 8;
    const int m0   = blockIdx.x * 256 + w * 64;
    const int o0   = blockIdx.y * 64;
    const int kbase = blockIdx.z * KPS;

    unsigned char* wlds = ldsA + w * (64*136);

    /* ---- stage A: 64 rows x 128 q-bytes, coalesced ---- */
    {
        const int rsub = lane >> 3;     /* 0..7 */
        const int c    = lane & 7;      /* 16B chunk */
        const unsigned int koff = (unsigned int)(kbase >> 3);
        #pragma unroll
        for (int j = 0; j < 8; ++j) {
            const int row = j*8 + rsub;
            uint4 v = *(const uint4*)(q + (size_t)(m0 + row)*KQ + koff + c*16);
            unsigned char* dst = wlds + row*136 + c*16;
            uint2 lo; lo.x = v.x; lo.y = v.y;
            uint2 hi; hi.x = v.z; hi.y = v.w;
            *(uint2*)dst = lo;
            *(uint2*)(dst + 8) = hi;
        }
    }

    f32x4 acc[4][4] = {};

    unsigned int boff[8];
    #pragma unroll
    for (int nf = 0; nf < 4; ++nf)
        #pragma unroll
        for (int kf = 0; kf < 2; ++kf)
            boff[nf*2+kf] = (unsigned int)(o0 + nf*16 + l15) * KP + kbase + kf*32 + lq*8;

    /* B double-buffer: preload it=0 */
    f16x8 bf0[8], bf1[8];
    #pragma unroll
    for (int j = 0; j < 8; ++j)
        bf0[j] = *(const f16x8*)(W + boff[j]);

    const unsigned char* ards = wlds + l15*136;

    #pragma unroll 2
    for (int it = 0; it < NIT; ++it) {
        const f16x8* cur = (it & 1) ? bf1 : bf0;
        f16x8*       nxt = (it & 1) ? bf0 : bf1;
        if (it + 1 < NIT) {
            #pragma unroll
            for (int j = 0; j < 8; ++j)
                nxt[j] = *(const f16x8*)(W + boff[j] + (it+1)*64);
        }
        uint2 qd[4];
        #pragma unroll
        for (int mf = 0; mf < 4; ++mf)
            qd[mf] = *(const uint2*)(ards + mf*(16*136) + it*8);
        #pragma unroll
        for (int kf = 0; kf < 2; ++kf) {
            #pragma unroll
            for (int mf = 0; mf < 4; ++mf) {
                unsigned int byte = ((kf ? qd[mf].y : qd[mf].x) >> sh8) & 0xFFu;
                f16x8 a = expand_byte(byte);
                #pragma unroll
                for (int nf = 0; nf < 4; ++nf)
                    acc[mf][nf] = __builtin_amdgcn_mfma_f32_16x16x32_f16(a, cur[nf*2+kf], acc[mf][nf], 0, 0, 0);
            }
        }
    }

    /* epilogue: C/D layout col = lane&15, row = (lane>>4)*4 + r  (m89) */
    if (EPI1) {
        _Float16* out = (_Float16*)outv;
        const float mn1 = dec_f(scal[0]);
        float bv[4];
        #pragma unroll
        for (int nf = 0; nf < 4; ++nf) bv[nf] = mn1 * braw[o0 + nf*16 + l15];
        float tmn = 3.0e38f, tmx = -3.0e38f;
        #pragma unroll
        for (int mf = 0; mf < 4; ++mf) {
            const int mr = m0 + mf*16 + lq*4;
            #pragma unroll
            for (int nf = 0; nf < 4; ++nf) {
                const int oc = o0 + nf*16 + l15;
                #pragma unroll
                for (int r = 0; r < 4; ++r) {
                    float v = fmaxf(acc[mf][nf][r] + bv[nf], 0.0f);
                    _Float16 v16 = (_Float16)v;
                    float vr = (float)v16;          /* min/max of fp16-rounded h */
                    tmn = fminf(tmn, vr); tmx = fmaxf(tmx, vr);
                    out[(size_t)(mr + r)*N + oc] = v16;
                }
            }
        }
        float* red = (float*)ldsA;
        __syncthreads();
        red[tid] = tmn; red[256 + tid] = tmx;
        __syncthreads();
        for (int s = 128; s > 0; s >>= 1) {
            if (tid < s) {
                red[tid]       = fminf(red[tid],       red[tid + s]);
                red[256 + tid] = fmaxf(red[256 + tid], red[256 + tid + s]);
            }
            __syncthreads();
        }
        if (tid == 0) { atomicMin(&scal[2], enc_f(red[0])); atomicMax(&scal[3], enc_f(red[256])); }
    } else {
        _Float16* op = (_Float16*)outv + (size_t)blockIdx.z * ((size_t)M1 * N);
        #pragma unroll
        for (int mf = 0; mf < 4; ++mf) {
            const int mr = m0 + mf*16 + lq*4;
            #pragma unroll
            for (int nf = 0; nf < 4; ++nf) {
                const int oc = o0 + nf*16 + l15;
                #pragma unroll
                for (int r = 0; r < 4; ++r)
                    op[(size_t)(mr + r)*N + oc] = (_Float16)acc[mf][nf][r];
            }
        }
    }
}

/* gate/extract from fp16 split-K partials -> sigmoid*tanh*mask, sum over neighbors.
   2 features per thread, packed fp16x2 loads. */
__global__ __launch_bounds__(256) void k_nbr(const _Float16* __restrict__ zp,
                                             const float* __restrict__ b2raw,
                                             const unsigned int* __restrict__ scal,
                                             const float* __restrict__ mask,
                                             float* __restrict__ ns) {
    const size_t SP = (size_t)M1 * N2;
    int tid = threadIdx.x;
    int r = blockIdx.x*8 + (tid >> 5);    /* 0..1535 */
    int f2 = (tid & 31) * 2;
    const float mn2 = dec_f(scal[2]);
    float bg0 = mn2 * b2raw[f2],      bg1 = mn2 * b2raw[f2+1];
    float be0 = mn2 * b2raw[64 + f2], be1 = mn2 * b2raw[65 + f2];
    float s0 = 0.f, s1 = 0.f;
    #pragma unroll
    for (int n = 0; n < NBR_; n++) {
        int m = r*NBR_ + n;
        size_t base = (size_t)m * N2;
        float g0 = bg0, g1 = bg1, e0 = be0, e1 = be1;
        #pragma unroll
        for (int z = 0; z < SPLIT2; z++) {
            f16x2 gv = *(const f16x2*)(zp + z*SP + base + f2);
            f16x2 ev = *(const f16x2*)(zp + z*SP + base + 64 + f2);
            g0 += (float)gv[0]; g1 += (float)gv[1];
            e0 += (float)ev[0]; e1 += (float)ev[1];
        }
        float mk = mask[m];
        s0 += (1.0f / (1.0f + expf(-g0))) * tanhf(e0) * mk;
        s1 += (1.0f / (1.0f + expf(-g1))) * tanhf(e1) * mk;
    }
    float2 o; o.x = s0; o.y = s1;
    *(float2*)&ns[r*64 + f2] = o;
}

/* BatchNorm (batch stats over 1536 rows) + residual + relu; one block per feature */
__global__ __launch_bounds__(256) void k_bn(const float* __restrict__ ns,
                                            const float* __restrict__ node,
                                            const float* __restrict__ gamma,
                                            const float* __restrict__ beta,
                                            float* __restrict__ out) {
    int f = blockIdx.x;
    int tid = threadIdx.x;
    float x[6];
    float s = 0.f, ss = 0.f;
    #pragma unroll
    for (int k = 0; k < 6; k++) {
        int r = tid + k*256;
        x[k] = ns[r*64 + f];
        s += x[k]; ss += x[k]*x[k];
    }
    __shared__ float rs[256], rss[256];
    rs[tid] = s; rss[tid] = ss; __syncthreads();
    for (int st = 128; st > 0; st >>= 1) {
        if (tid < st) { rs[tid] += rs[tid+st]; rss[tid] += rss[tid+st]; }
        __syncthreads();
    }
    float mean = rs[0] / 1536.0f;
    float var  = rss[0] / 1536.0f - mean*mean;
    float denom = sqrtf(var + 1e-5f);
    float g = gamma[f], bt = beta[f];
    #pragma unroll
    for (int k = 0; k < 6; k++) {
        int r = tid + k*256;
        float v = node[r*64 + f] + ((x[k] - mean) / denom * g + bt);
        out[r*64 + f] = fmaxf(v, 0.f);
    }
}

extern "C" void kernel_launch(void* const* d_in, const int* in_sizes, int n_in,
                              void* d_out, int out_size, void* d_ws, size_t ws_size,
                              hipStream_t stream) {
    const float* node  = (const float*)d_in[0];
    const float* edge  = (const float*)d_in[1];
    const float* mask  = (const float*)d_in[2];
    const float* cond1 = (const float*)d_in[3];
    const float* cond2 = (const float*)d_in[4];
    const float* eps1  = (const float*)d_in[5];
    const float* eps2  = (const float*)d_in[6];
    const float* gamma = (const float*)d_in[7];
    const float* beta  = (const float*)d_in[8];
    float* out = (float*)d_out;
    char* ws = (char*)d_ws;

    unsigned int*  scal = (unsigned int*)(ws + OFF_SCAL);
    float* b1raw = (float*)(ws + OFF_B1R);
    float* b2raw = (float*)(ws + OFF_B2R);
    unsigned char* q1 = (unsigned char*)(ws + OFF_Q1);
    _Float16* W1e = (_Float16*)(ws + OFF_W1E);
    _Float16* W2e = (_Float16*)(ws + OFF_W2E);
    unsigned char* q2 = (unsigned char*)(ws + OFF_Q2);
    _Float16* h  = (_Float16*)(ws + OFF_H);
    _Float16* zp = (_Float16*)(ws + OFF_ZP);
    float*    ns = (float*)(ws + OFF_NS);

    k_init<<<1, 1024, 0, stream>>>(scal, b1raw, b2raw);
    k_minmax_c1<<<512, 256, 0, stream>>>(node, edge, scal);
    k_prep_w16<K1Q, N1, 0, false><<<(N1*K1Q + 255)/256, 256, 0, stream>>>(cond1, eps1, scal, b1raw, W1e);
    k_quant_c1<<<(M1*32)/256, 256, 0, stream>>>(node, edge, scal, (unsigned int*)q1);
    kge<K1Q, N1, 1, true><<<dim3(M1/256, N1/64, 1), 256, 0, stream>>>(q1, W1e, b1raw, h, scal);
    k_prep_w16<K2Q, N2, 2, true><<<(N2*K2Q + 255)/256, 256, 0, stream>>>(cond2, eps2, scal, b2raw, W2e);
    k_quant_h<<<(M1*512/8)/256, 256, 0, stream>>>(h, scal, (unsigned int*)q2);
    kge<K2Q, N2, SPLIT2, false><<<dim3(M1/256, N2/64, SPLIT2), 256, 0, stream>>>(q2, W2e, b2raw, zp, scal);
    k_nbr<<<R_/8, 256, 0, stream>>>(zp, b2raw, scal, mask, ns);
    k_bn<<<64, 256, 0, stream>>>(ns, node, gamma, beta, out);
}

// Round 6
// 230.936 us; speedup vs baseline: 1.1440x; 1.0028x over previous
//
#include <hip/hip_runtime.h>
#include <stdint.h>

#define B_    16
#define AT_   96
#define NBR_  12
#define FN_   64
#define FE_   64
#define M1    (B_*AT_*NBR_)   /* 18432 */
#define R_    (B_*AT_)        /* 1536  */
#define K1Q   128             /* layer-1 input features (bytes per row) */
#define N1    512             /* H1 */
#define K2Q   512
#define N2    128
#define SPLIT2 4

typedef _Float16 f16x8 __attribute__((ext_vector_type(8)));
typedef _Float16 f16x2 __attribute__((ext_vector_type(2)));
typedef float    f32x4 __attribute__((ext_vector_type(4)));

/* ---- workspace layout (bytes) ---- */
#define OFF_SCAL  0u
#define OFF_B1R   256u                                  /* fp32 512  */
#define OFF_B2R   (OFF_B1R + 2048u)                     /* fp32 128  */
#define OFF_Q1    4096u                                 /* u8 M1*128 = 2.25 MB */
#define OFF_W1E   (OFF_Q1  + (size_t)M1*K1Q)            /* fp16 512*1024 = 1 MB */
#define OFF_W2E   (OFF_W1E + (size_t)N1*K1Q*8*2)        /* fp16 128*4096 = 1 MB */
#define OFF_Q2    (OFF_W2E + (size_t)N2*K2Q*8*2)        /* u8 M1*512 = 9 MB */
#define OFF_H     (OFF_Q2  + (size_t)M1*K2Q)            /* fp16 M1*512 = 18.87 MB */
#define OFF_ZP    OFF_H                                  /* fp16 4*M1*128; h dead after quant_h */
#define OFF_NS    (OFF_H   + (size_t)M1*N1*2)           /* fp32 1536*64 */

__device__ __forceinline__ unsigned int enc_f(float f) {
    unsigned int u = __float_as_uint(f);
    return (u & 0x80000000u) ? ~u : (u | 0x80000000u);
}
__device__ __forceinline__ float dec_f(unsigned int u) {
    return __uint_as_float((u & 0x80000000u) ? (u & 0x7FFFFFFFu) : ~u);
}

/* init scal + zero bias accumulators (ws is poisoned 0xAA every launch) */
__global__ void k_init(unsigned int* scal, float* b1raw, float* b2raw) {
    int t = threadIdx.x;
    if (t == 0) { scal[0] = 0xFFFFFFFFu; scal[1] = 0u; scal[2] = 0xFFFFFFFFu; scal[3] = 0u; }
    if (t < N1) b1raw[t] = 0.f;
    if (t < N2) b2raw[t] = 0.f;
}

__global__ __launch_bounds__(256) void k_minmax_c1(const float* __restrict__ node,
                                                   const float* __restrict__ edge,
                                                   unsigned int* __restrict__ scal) {
    const int nn4 = (B_*AT_*FN_)/4;       /* 24576  */
    const int tot4 = nn4 + (M1*FE_)/4;    /* 319488 */
    float mn = 3.0e38f, mx = -3.0e38f;
    for (int idx = blockIdx.x*blockDim.x + threadIdx.x; idx < tot4; idx += gridDim.x*blockDim.x) {
        float4 x = (idx < nn4) ? ((const float4*)node)[idx] : ((const float4*)edge)[idx - nn4];
        mn = fminf(mn, fminf(fminf(x.x, x.y), fminf(x.z, x.w)));
        mx = fmaxf(mx, fmaxf(fmaxf(x.x, x.y), fmaxf(x.z, x.w)));
    }
    __shared__ float smn[256], smx[256];
    smn[threadIdx.x] = mn; smx[threadIdx.x] = mx; __syncthreads();
    for (int s = 128; s > 0; s >>= 1) {
        if (threadIdx.x < s) {
            smn[threadIdx.x] = fminf(smn[threadIdx.x], smn[threadIdx.x+s]);
            smx[threadIdx.x] = fmaxf(smx[threadIdx.x], smx[threadIdx.x+s]);
        }
        __syncthreads();
    }
    if (threadIdx.x == 0) { atomicMin(&scal[0], enc_f(smn[0])); atomicMax(&scal[1], enc_f(smx[0])); }
}

/* expanded fp16 weights, o-major: We[o][k=i*8+b] = fp16( (w+0.1|w|eps_b) * 2^b * s )
   + fused bias-sum accumulation (wave-reduce, 1 atomic per wave) */
template<int KQ, int N, int SBASE, bool USE_SECOND>
__global__ __launch_bounds__(256) void k_prep_w16(const float* __restrict__ w_clean,
                                                  const float* __restrict__ eps,
                                                  const unsigned int* __restrict__ scal,
                                                  float* __restrict__ braw,
                                                  _Float16* __restrict__ We) {
    int idx = blockIdx.x*blockDim.x + threadIdx.x;   /* one thread per (o,i) */
    if (idx >= N*KQ) return;
    int o = idx / KQ;
    float mn = dec_f(scal[SBASE]), mx = dec_f(scal[SBASE+1]);
    float s = (mx - mn) * (1.0f/255.0f);
    float w = w_clean[idx];
    float aw = fabsf(w) * 0.1f;
    union { _Float16 h[8]; uint4 u; } pk;
    float p = s;
    float v7 = 0.f;
    #pragma unroll
    for (int b = 0; b < 8; b++) {
        float e = eps[(size_t)b*N*KQ + idx];
        float v = w + e*aw;
        if (b == 7) v7 = v;
        pk.h[b] = (_Float16)(v * p);
        p *= 2.0f;
    }
    *(uint4*)&We[(size_t)idx*8] = pk.u;
    float bv = USE_SECOND ? w_clean[(size_t)N*KQ + idx] : v7;
    #pragma unroll
    for (int off = 32; off > 0; off >>= 1) bv += __shfl_down(bv, off);
    if ((threadIdx.x & 63) == 0) atomicAdd(&braw[o], bv);
}

/* quantize c1 -> q1 m-major [m][128] bytes; thread per output dword */
__global__ __launch_bounds__(256) void k_quant_c1(const float* __restrict__ node,
                                                  const float* __restrict__ edge,
                                                  const unsigned int* __restrict__ scal,
                                                  unsigned int* __restrict__ q1) {
    int idx = blockIdx.x*256 + threadIdx.x;   /* < M1*32 */
    int m = idx >> 5, dw = idx & 31;
    const float mn = dec_f(scal[0]), rng = dec_f(scal[1]) - mn;
    float4 x;
    if (dw < 16) x = *(const float4*)&node[(m/NBR_)*FN_ + dw*4];
    else         x = *(const float4*)&edge[(size_t)m*FE_ + (dw-16)*4];
    unsigned int b0 = (unsigned char)(int)((x.x - mn) / rng * 255.0f);
    unsigned int b1 = (unsigned char)(int)((x.y - mn) / rng * 255.0f);
    unsigned int b2 = (unsigned char)(int)((x.z - mn) / rng * 255.0f);
    unsigned int b3 = (unsigned char)(int)((x.w - mn) / rng * 255.0f);
    q1[idx] = b0 | (b1 << 8) | (b2 << 16) | (b3 << 24);
}

/* quantize fp16 h -> q2 m-major [m][512] bytes; thread per 8 elements */
__global__ __launch_bounds__(256) void k_quant_h(const _Float16* __restrict__ h,
                                                 const unsigned int* __restrict__ scal,
                                                 unsigned int* __restrict__ q2) {
    int idx = blockIdx.x*256 + threadIdx.x;   /* < M1*512/8 */
    const float mn = dec_f(scal[2]), rng = dec_f(scal[3]) - mn;
    f16x8 v = *(const f16x8*)(h + (size_t)idx*8);
    unsigned int lo = 0, hi = 0;
    #pragma unroll
    for (int j = 0; j < 4; j++) {
        float x = (float)v[j];
        lo |= ((unsigned int)(unsigned char)(int)((x - mn) / rng * 255.0f)) << (j*8);
    }
    #pragma unroll
    for (int j = 0; j < 4; j++) {
        float x = (float)v[4+j];
        hi |= ((unsigned int)(unsigned char)(int)((x - mn) / rng * 255.0f)) << (j*8);
    }
    uint2 o; o.x = lo; o.y = hi;
    *(uint2*)&q2[idx*2] = o;
}

__device__ __forceinline__ f16x8 expand_byte(unsigned int byte) {
    /* 8 bits -> 8 packed fp16 in {0.0, 1.0}; pairs via r2 = b | b<<15 */
    unsigned int r2 = byte | (byte << 15);
    union { unsigned int u[4]; f16x8 h; } t;
    t.u[0] = ( r2       & 0x00010001u) * 0x3C00u;
    t.u[1] = ((r2 >> 2) & 0x00010001u) * 0x3C00u;
    t.u[2] = ((r2 >> 4) & 0x00010001u) * 0x3C00u;
    t.u[3] = ((r2 >> 6) & 0x00010001u) * 0x3C00u;
    return t.h;
}

#define COMPUTE(qd, bf)  do { \
    _Pragma("unroll") for (int kf = 0; kf < 2; ++kf) { \
      _Pragma("unroll") for (int mf = 0; mf < 4; ++mf) { \
        unsigned int byte_ = ((kf ? qd[mf].y : qd[mf].x) >> sh8) & 0xFFu; \
        f16x8 a_ = expand_byte(byte_); \
        _Pragma("unroll") for (int nf = 0; nf < 4; ++nf) \
          acc[mf][nf] = __builtin_amdgcn_mfma_f32_16x16x32_f16(a_, bf[nf*2+kf], acc[mf][nf], 0, 0, 0); \
      } } } while (0)

#define LOADB(bf, itv) { _Pragma("unroll") for (int jb = 0; jb < 8; ++jb) \
    bf[jb] = *(const f16x8*)(W + boff[jb] + (unsigned)(itv)*64); }

#define LOADQ(qd, itv) { _Pragma("unroll") for (int mf = 0; mf < 4; ++mf) \
    qd[mf] = *(const uint2*)(ards + mf*(16*136) + (itv)*8); }

/* MFMA bit-plane GEMM v6 "kgh":
   - wave-private LDS A staging (coalesced, conflict-free, no barriers in loop)
   - B: 4 NAMED register buffers (compile-time indices only -> guaranteed
     promotion), prefetch distance 3 bodies (~600+ cyc) to cover L3 latency
   - XCD swizzle: blockIdx%8 -> XCD (dispatch heuristic); each XCD owns a 1/8
     m-slice so its cold L2 warms on ~1-2 MB instead of the whole problem
   - __launch_bounds__(256,2): 256 unified regs, est ~190 arch + 64 acc */
template<int KQ, int N, int SPLITK, bool EPI1>
__global__ __launch_bounds__(256, 2) void kgh(const unsigned char* __restrict__ q,
                                              const _Float16* __restrict__ W,
                                              const float* __restrict__ braw,
                                              void* __restrict__ outv,
                                              unsigned int* __restrict__ scal) {
    constexpr int KP  = KQ * 8;        /* total bit-planes */
    constexpr int KPS = KP / SPLITK;   /* planes per z-split (1024 both layers) */
    constexpr int NIT = KPS / 64;      /* 16 */
    constexpr int NOT_ = N / 64;
    constexpr int MT  = M1 / 256;      /* 72 m-tiles */
    constexpr int MPX = MT / 8;        /* 9 per XCD */
    __shared__ __align__(16) unsigned char ldsA[4*64*136];   /* 34816 B */

    const int tid  = threadIdx.x;
    const int lane = tid & 63;
    const int w    = tid >> 6;
    const int l15  = lane & 15;
    const int lq   = lane >> 4;
    const int sh8  = lq * 8;

    /* XCD-aware decode: lin%8 = XCD (round-robin dispatch heuristic) */
    const int lin  = blockIdx.x;
    const int xcd  = lin & 7;
    const int jj   = lin >> 3;            /* 0..71 */
    const int mt   = xcd * MPX + (jj % MPX);
    const int rest = jj / MPX;            /* 0..NOT_*SPLITK-1 */
    const int ot   = rest % NOT_;
    const int zt   = rest / NOT_;

    const int m0    = mt*256 + w*64;
    const int o0    = ot*64;
    const int kbase = zt * KPS;

    unsigned char* wlds = ldsA + w * (64*136);

    /* ---- stage A: 64 rows x 128 q-bytes, coalesced ---- */
    {
        const int rsub = lane >> 3;     /* 0..7 */
        const int c    = lane & 7;      /* 16B chunk */
        const unsigned int koff = (unsigned int)(kbase >> 3);
        #pragma unroll
        for (int j = 0; j < 8; ++j) {
            const int row = j*8 + rsub;
            uint4 v = *(const uint4*)(q + (size_t)(m0 + row)*KQ + koff + c*16);
            unsigned char* dst = wlds + row*136 + c*16;
            uint2 lo; lo.x = v.x; lo.y = v.y;
            uint2 hi; hi.x = v.z; hi.y = v.w;
            *(uint2*)dst = lo;
            *(uint2*)(dst + 8) = hi;
        }
    }

    f32x4 acc[4][4] = {};

    unsigned int boff[8];
    #pragma unroll
    for (int nf = 0; nf < 4; ++nf)
        #pragma unroll
        for (int kf = 0; kf < 2; ++kf)
            boff[nf*2+kf] = (unsigned int)(o0 + nf*16 + l15) * KP + kbase + kf*32 + lq*8;

    const unsigned char* ards = wlds + l15*136;

    f16x8 bufA[8], bufB[8], bufC[8], bufD[8];
    uint2 qdA[4], qdB[4];
    LOADB(bufA, 0); LOADB(bufB, 1); LOADB(bufC, 2);
    LOADQ(qdA, 0);

    #pragma unroll 1
    for (int it = 0; it < NIT; it += 4) {
        LOADB(bufD, it+3);
        LOADQ(qdB, it+1);
        COMPUTE(qdA, bufA);
        if (it+4 < NIT) LOADB(bufA, it+4);
        LOADQ(qdA, it+2);
        COMPUTE(qdB, bufB);
        if (it+5 < NIT) LOADB(bufB, it+5);
        LOADQ(qdB, it+3);
        COMPUTE(qdA, bufC);
        if (it+6 < NIT) LOADB(bufC, it+6);
        if (it+4 < NIT) LOADQ(qdA, it+4);
        COMPUTE(qdB, bufD);
    }

    /* epilogue: C/D layout col = lane&15, row = (lane>>4)*4 + r  (m89) */
    if (EPI1) {
        _Float16* out = (_Float16*)outv;
        const float mn1 = dec_f(scal[0]);
        float bv[4];
        #pragma unroll
        for (int nf = 0; nf < 4; ++nf) bv[nf] = mn1 * braw[o0 + nf*16 + l15];
        float tmn = 3.0e38f, tmx = -3.0e38f;
        #pragma unroll
        for (int mf = 0; mf < 4; ++mf) {
            const int mr = m0 + mf*16 + lq*4;
            #pragma unroll
            for (int nf = 0; nf < 4; ++nf) {
                const int oc = o0 + nf*16 + l15;
                #pragma unroll
                for (int r = 0; r < 4; ++r) {
                    float v = fmaxf(acc[mf][nf][r] + bv[nf], 0.0f);
                    _Float16 v16 = (_Float16)v;
                    float vr = (float)v16;          /* min/max of fp16-rounded h */
                    tmn = fminf(tmn, vr); tmx = fmaxf(tmx, vr);
                    out[(size_t)(mr + r)*N + oc] = v16;
                }
            }
        }
        float* red = (float*)ldsA;
        __syncthreads();
        red[tid] = tmn; red[256 + tid] = tmx;
        __syncthreads();
        for (int s = 128; s > 0; s >>= 1) {
            if (tid < s) {
                red[tid]       = fminf(red[tid],       red[tid + s]);
                red[256 + tid] = fmaxf(red[256 + tid], red[256 + tid + s]);
            }
            __syncthreads();
        }
        if (tid == 0) { atomicMin(&scal[2], enc_f(red[0])); atomicMax(&scal[3], enc_f(red[256])); }
    } else {
        _Float16* op = (_Float16*)outv + (size_t)zt * ((size_t)M1 * N);
        #pragma unroll
        for (int mf = 0; mf < 4; ++mf) {
            const int mr = m0 + mf*16 + lq*4;
            #pragma unroll
            for (int nf = 0; nf < 4; ++nf) {
                const int oc = o0 + nf*16 + l15;
                #pragma unroll
                for (int r = 0; r < 4; ++r)
                    op[(size_t)(mr + r)*N + oc] = (_Float16)acc[mf][nf][r];
            }
        }
    }
}

/* gate/extract from fp16 split-K partials -> sigmoid*tanh*mask, sum over neighbors.
   2 features per thread, packed fp16x2 loads. */
__global__ __launch_bounds__(256) void k_nbr(const _Float16* __restrict__ zp,
                                             const float* __restrict__ b2raw,
                                             const unsigned int* __restrict__ scal,
                                             const float* __restrict__ mask,
                                             float* __restrict__ ns) {
    const size_t SP = (size_t)M1 * N2;
    int tid = threadIdx.x;
    int r = blockIdx.x*8 + (tid >> 5);    /* 0..1535 */
    int f2 = (tid & 31) * 2;
    const float mn2 = dec_f(scal[2]);
    float bg0 = mn2 * b2raw[f2],      bg1 = mn2 * b2raw[f2+1];
    float be0 = mn2 * b2raw[64 + f2], be1 = mn2 * b2raw[65 + f2];
    float s0 = 0.f, s1 = 0.f;
    #pragma unroll
    for (int n = 0; n < NBR_; n++) {
        int m = r*NBR_ + n;
        size_t base = (size_t)m * N2;
        float g0 = bg0, g1 = bg1, e0 = be0, e1 = be1;
        #pragma unroll
        for (int z = 0; z < SPLIT2; z++) {
            f16x2 gv = *(const f16x2*)(zp + z*SP + base + f2);
            f16x2 ev = *(const f16x2*)(zp + z*SP + base + 64 + f2);
            g0 += (float)gv[0]; g1 += (float)gv[1];
            e0 += (float)ev[0]; e1 += (float)ev[1];
        }
        float mk = mask[m];
        s0 += (1.0f / (1.0f + expf(-g0))) * tanhf(e0) * mk;
        s1 += (1.0f / (1.0f + expf(-g1))) * tanhf(e1) * mk;
    }
    float2 o; o.x = s0; o.y = s1;
    *(float2*)&ns[r*64 + f2] = o;
}

/* BatchNorm (batch stats over 1536 rows) + residual + relu; one block per feature */
__global__ __launch_bounds__(256) void k_bn(const float* __restrict__ ns,
                                            const float* __restrict__ node,
                                            const float* __restrict__ gamma,
                                            const float* __restrict__ beta,
                                            float* __restrict__ out) {
    int f = blockIdx.x;
    int tid = threadIdx.x;
    float x[6];
    float s = 0.f, ss = 0.f;
    #pragma unroll
    for (int k = 0; k < 6; k++) {
        int r = tid + k*256;
        x[k] = ns[r*64 + f];
        s += x[k]; ss += x[k]*x[k];
    }
    __shared__ float rs[256], rss[256];
    rs[tid] = s; rss[tid] = ss; __syncthreads();
    for (int st = 128; st > 0; st >>= 1) {
        if (tid < st) { rs[tid] += rs[tid+st]; rss[tid] += rss[tid+st]; }
        __syncthreads();
    }
    float mean = rs[0] / 1536.0f;
    float var  = rss[0] / 1536.0f - mean*mean;
    float denom = sqrtf(var + 1e-5f);
    float g = gamma[f], bt = beta[f];
    #pragma unroll
    for (int k = 0; k < 6; k++) {
        int r = tid + k*256;
        float v = node[r*64 + f] + ((x[k] - mean) / denom * g + bt);
        out[r*64 + f] = fmaxf(v, 0.f);
    }
}

extern "C" void kernel_launch(void* const* d_in, const int* in_sizes, int n_in,
                              void* d_out, int out_size, void* d_ws, size_t ws_size,
                              hipStream_t stream) {
    const float* node  = (const float*)d_in[0];
    const float* edge  = (const float*)d_in[1];
    const float* mask  = (const float*)d_in[2];
    const float* cond1 = (const float*)d_in[3];
    const float* cond2 = (const float*)d_in[4];
    const float* eps1  = (const float*)d_in[5];
    const float* eps2  = (const float*)d_in[6];
    const float* gamma = (const float*)d_in[7];
    const float* beta  = (const float*)d_in[8];
    float* out = (float*)d_out;
    char* ws = (char*)d_ws;

    unsigned int*  scal = (unsigned int*)(ws + OFF_SCAL);
    float* b1raw = (float*)(ws + OFF_B1R);
    float* b2raw = (float*)(ws + OFF_B2R);
    unsigned char* q1 = (unsigned char*)(ws + OFF_Q1);
    _Float16* W1e = (_Float16*)(ws + OFF_W1E);
    _Float16* W2e = (_Float16*)(ws + OFF_W2E);
    unsigned char* q2 = (unsigned char*)(ws + OFF_Q2);
    _Float16* h  = (_Float16*)(ws + OFF_H);
    _Float16* zp = (_Float16*)(ws + OFF_ZP);
    float*    ns = (float*)(ws + OFF_NS);

    k_init<<<1, 1024, 0, stream>>>(scal, b1raw, b2raw);
    k_minmax_c1<<<512, 256, 0, stream>>>(node, edge, scal);
    k_prep_w16<K1Q, N1, 0, false><<<(N1*K1Q + 255)/256, 256, 0, stream>>>(cond1, eps1, scal, b1raw, W1e);
    k_quant_c1<<<(M1*32)/256, 256, 0, stream>>>(node, edge, scal, (unsigned int*)q1);
    kgh<K1Q, N1, 1, true><<<576, 256, 0, stream>>>(q1, W1e, b1raw, h, scal);
    k_prep_w16<K2Q, N2, 2, true><<<(N2*K2Q + 255)/256, 256, 0, stream>>>(cond2, eps2, scal, b2raw, W2e);
    k_quant_h<<<(M1*512/8)/256, 256, 0, stream>>>(h, scal, (unsigned int*)q2);
    kgh<K2Q, N2, SPLIT2, false><<<576, 256, 0, stream>>>(q2, W2e, b2raw, zp, scal);
    k_nbr<<<R_/8, 256, 0, stream>>>(zp, b2raw, scal, mask, ns);
    k_bn<<<64, 256, 0, stream>>>(ns, node, gamma, beta, out);
}